// Round 4
// 512.775 us; speedup vs baseline: 1.0136x; 1.0136x over previous
//
#include <hip/hip_runtime.h>
#include <stdint.h>

typedef __bf16 bf16_t;
typedef __bf16 bf16x8 __attribute__((ext_vector_type(8)));
typedef __bf16 bf16x4v __attribute__((ext_vector_type(4)));
typedef float f32x16 __attribute__((ext_vector_type(16)));

#define AS_GLOBAL __attribute__((address_space(1)))
#define AS_LDS    __attribute__((address_space(3)))

static constexpr int NN   = 8192;   // nodes
static constexpr int DIN  = 512;
static constexpr int DOUT = 512;
static constexpr int SPLITK = 2;    // R2's measured-best; splitk4 regressed (R5); splitk4+dbuf
                                    // would need 256KB LDS for 4 blocks/CU -> impossible anyway

// 16B async global->LDS copy (global_load_lds_dwordx4).
__device__ __forceinline__ void async_cp16(const bf16_t* g, bf16_t* l) {
  __builtin_amdgcn_global_load_lds((AS_GLOBAL unsigned int*)g,
                                   (AS_LDS unsigned int*)l, 16, 0, 0);
}

// ---------------------------------------------------------------------------
// K1: d[i] = rsqrt(sum_k adj[i,k] + 1), adjb = bf16(adj + I).
// The +I fold means gemm1 computes (A+I)@Y directly -> no +Y epilogue term.
// ---------------------------------------------------------------------------
__global__ __launch_bounds__(256) void k_rowsum_convert(
    const float* __restrict__ adj, bf16_t* __restrict__ adjb,
    float* __restrict__ d) {
  const int row = blockIdx.x;
  const int t = threadIdx.x;
  const float4* rf4 = (const float4*)(adj + (size_t)row * NN);
  bf16_t* outp = adjb + (size_t)row * NN;
  const int diagF4 = row >> 2;
  float sum = 0.f;
#pragma unroll
  for (int c = 0; c < 8; ++c) {
    int f4i = c * 256 + t;               // 2048 float4 per row
    float4 a = rf4[f4i];
    sum += a.x + a.y + a.z + a.w;
    bf16x4v o;
    o[0] = (bf16_t)a.x; o[1] = (bf16_t)a.y; o[2] = (bf16_t)a.z; o[3] = (bf16_t)a.w;
    if (f4i == diagF4) {                 // fold identity into the bf16 matrix
      int s = row & 3;
      float vv = s == 0 ? a.x : s == 1 ? a.y : s == 2 ? a.z : a.w;
      o[s] = (bf16_t)(vv + 1.0f);
    }
    *(bf16x4v*)(outp + f4i * 4) = o;
  }
#pragma unroll
  for (int off = 32; off > 0; off >>= 1) sum += __shfl_down(sum, off);
  __shared__ float red[4];
  if ((t & 63) == 0) red[t >> 6] = sum;
  __syncthreads();
  if (t == 0) {
    float s = red[0] + red[1] + red[2] + red[3] + 1.0f;  // +1 for identity
    d[row] = rsqrtf(s);
  }
}

// ---------------------------------------------------------------------------
// K2: dxb[i][k] = bf16(d[i] * x[i][k])   (8192 x 512, unit stride)
// ---------------------------------------------------------------------------
__global__ __launch_bounds__(256) void k_dx(
    const float* __restrict__ x, const float* __restrict__ d,
    bf16_t* __restrict__ dxb) {
  int idx = blockIdx.x * 256 + threadIdx.x;   // float4 index
  int i = idx >> 7;                           // 128 f4 per row
  float4 v = *(const float4*)(x + (size_t)idx * 4);
  float s = d[i];
  bf16x4v o;
  o[0] = (bf16_t)(v.x * s); o[1] = (bf16_t)(v.y * s);
  o[2] = (bf16_t)(v.z * s); o[3] = (bf16_t)(v.w * s);
  *(bf16x4v*)(dxb + (size_t)idx * 4) = o;
}

// ---------------------------------------------------------------------------
// K3: Wb = bf16(W)
// ---------------------------------------------------------------------------
__global__ __launch_bounds__(256) void k_convert_w(
    const float* __restrict__ W, bf16_t* __restrict__ Wb) {
  int idx = blockIdx.x * 256 + threadIdx.x;
  float4 v = *(const float4*)(W + (size_t)idx * 4);
  bf16x4v o;
  o[0] = (bf16_t)v.x; o[1] = (bf16_t)v.y; o[2] = (bf16_t)v.z; o[3] = (bf16_t)v.w;
  *(bf16x4v*)(Wb + (size_t)idx * 4) = o;
}

// ---------------------------------------------------------------------------
// GEMM core, NT, bf16, 128x128 tile, 2-phase double-buffered (T3-minimum):
//   prologue stage tile0 -> loop { stage tile t+1 into buf^1; vmcnt(8) (tile t
//   landed, next 8 loads stay in flight); s_barrier; ds_read+MFMA on buf;
//   lgkmcnt(0); s_barrier; flip }.
// Raw s_barrier + counted vmcnt replaces __syncthreads() -- the old structure's
// vmcnt(0) drain exposed full HBM latency every 64-K step (the ~350us theory).
// 256 thr = 4 waves 2x2, wave 64x64 via 2x2 frags of v_mfma_f32_32x32x16_bf16.
// C/D: col=lane&31, row=(reg&3)+8*(reg>>2)+4*(lane>>5) [m74/m101].
// XOR-swizzled LDS (verified in prior session): staging lane permutes its
// global source chunk, frag reads XOR back -> conflict-floor b128 reads.
// ---------------------------------------------------------------------------
__device__ __forceinline__ void gemm_tile_128x128_db(
    const bf16_t* __restrict__ A, const bf16_t* __restrict__ B,
    int lda, int ldb, int m0, int n0, int kStart, int kEnd,
    bf16_t* As, bf16_t* Bs, f32x16 acc[2][2]) {
  const int t = threadIdx.x;
  const int lane = t & 63;
  const int wid = t >> 6;
  const int wm = wid >> 1, wn = wid & 1;
  const int l32 = lane & 31, half = lane >> 5;

  const int swz = (t & 7) ^ ((t >> 3) & 7);
  const bf16_t* gA = A + (size_t)(m0 + (t >> 3)) * lda + swz * 8 + kStart;
  const bf16_t* gB = B + (size_t)(n0 + (t >> 3)) * ldb + swz * 8 + kStart;
  const int xorc = lane & 7;
  const int nIter = (kEnd - kStart) >> 6;

  // prologue: stage tile 0 into buffer 0 (8 loads in flight)
#pragma unroll
  for (int i = 0; i < 4; ++i) {
    async_cp16(gA + (size_t)(i * 32) * lda, As + t * 8 + i * 2048);
    async_cp16(gB + (size_t)(i * 32) * ldb, Bs + t * 8 + i * 2048);
  }
  gA += 64; gB += 64;

  int cur = 0;
  for (int it = 0; it < nIter; ++it) {
    if (it + 1 < nIter) {
      const int nb = (cur ^ 1) * 8192;   // next buffer, elements
#pragma unroll
      for (int i = 0; i < 4; ++i) {
        async_cp16(gA + (size_t)(i * 32) * lda, As + nb + t * 8 + i * 2048);
        async_cp16(gB + (size_t)(i * 32) * ldb, Bs + nb + t * 8 + i * 2048);
      }
      gA += 64; gB += 64;
      // oldest 8 (current tile) done; newest 8 (next tile) remain in flight
      asm volatile("s_waitcnt vmcnt(8)" ::: "memory");
    } else {
      asm volatile("s_waitcnt vmcnt(0)" ::: "memory");
    }
    __builtin_amdgcn_s_barrier();        // all waves' current-tile loads landed

    const bf16_t* Ab = As + cur * 8192;
    const bf16_t* Bb = Bs + cur * 8192;
#pragma unroll
    for (int ks = 0; ks < 4; ++ks) {     // 4 K-steps of 16
      const int pchunk = ((ks * 2 + half) ^ xorc) * 8;
      bf16x8 av[2], bv[2];
#pragma unroll
      for (int f = 0; f < 2; ++f) {
        av[f] = *(const bf16x8*)(Ab + (wm * 64 + f * 32 + l32) * 64 + pchunk);
        bv[f] = *(const bf16x8*)(Bb + (wn * 64 + f * 32 + l32) * 64 + pchunk);
      }
#pragma unroll
      for (int fm = 0; fm < 2; ++fm)
#pragma unroll
        for (int fn = 0; fn < 2; ++fn)
          acc[fm][fn] = __builtin_amdgcn_mfma_f32_32x32x16_bf16(
              av[fm], bv[fn], acc[fm][fn], 0, 0, 0);
    }
    // all this wave's ds_reads drained before other waves may overwrite buf
    asm volatile("s_waitcnt lgkmcnt(0)" ::: "memory");
    __builtin_amdgcn_s_barrier();
    cur ^= 1;
  }
}

// ---------------------------------------------------------------------------
// K4: YT[j][i] = bf16( sum_k Wb[j,k] * dxb[i,k] )   (512 x 8192, K=512)
// Y = (d.x) @ W^T stored transposed so it is the k-contiguous B operand of K5.
// grid (4, 64) = 256 blocks = 1/CU.
// ---------------------------------------------------------------------------
__global__ __launch_bounds__(256) void k_gemmY(
    const bf16_t* __restrict__ Wb, const bf16_t* __restrict__ dxb,
    bf16_t* __restrict__ YT) {
  __shared__ __align__(16) bf16_t As[2 * 128 * 64];
  __shared__ __align__(16) bf16_t Bs[2 * 128 * 64];
  f32x16 acc[2][2];
#pragma unroll
  for (int a = 0; a < 2; ++a)
#pragma unroll
    for (int b = 0; b < 2; ++b)
#pragma unroll
      for (int r = 0; r < 16; ++r) acc[a][b][r] = 0.f;

  const int m0 = blockIdx.x * 128, n0 = blockIdx.y * 128;  // m over j, n over i
  gemm_tile_128x128_db(Wb, dxb, DIN, DIN, m0, n0, 0, DIN, As, Bs, acc);

  const int t = threadIdx.x;
  const int lane = t & 63, wid = t >> 6;
  const int wm = wid >> 1, wn = wid & 1;
  const int l32 = lane & 31, half = lane >> 5;
#pragma unroll
  for (int fm = 0; fm < 2; ++fm)
#pragma unroll
    for (int fn = 0; fn < 2; ++fn) {
      int gc = n0 + wn * 64 + fn * 32 + l32;
#pragma unroll
      for (int reg = 0; reg < 16; ++reg) {
        int gr = m0 + wm * 64 + fm * 32 + (reg & 3) + 8 * (reg >> 2) + 4 * half;
        YT[(size_t)gr * NN + gc] = (bf16_t)acc[fm][fn][reg];
      }
    }
}

// ---------------------------------------------------------------------------
// K5: gemm1 partials: part[kc][i][j] = sum_{k in chunk} adjb[i,k] * YT[j,k]
//   = ((A+I) @ Y) restricted to the K-chunk.  grid (64, 4, SPLITK) = 512
//   blocks, 2 resident/CU (64 KB LDS each) -> cross-block latency overlap.
// ---------------------------------------------------------------------------
__global__ __launch_bounds__(256) void k_gemm1(
    const bf16_t* __restrict__ adjb, const bf16_t* __restrict__ YT,
    float* __restrict__ part) {
  __shared__ __align__(16) bf16_t As[2 * 128 * 64];
  __shared__ __align__(16) bf16_t Bs[2 * 128 * 64];
  f32x16 acc[2][2];
#pragma unroll
  for (int a = 0; a < 2; ++a)
#pragma unroll
    for (int b = 0; b < 2; ++b)
#pragma unroll
      for (int r = 0; r < 16; ++r) acc[a][b][r] = 0.f;

  const int m0 = blockIdx.x * 128, n0 = blockIdx.y * 128;
  const int kc = blockIdx.z;
  const int kChunk = NN / SPLITK;           // 4096
  gemm_tile_128x128_db(adjb, YT, NN, NN, m0, n0, kc * kChunk, (kc + 1) * kChunk,
                       As, Bs, acc);

  const int t = threadIdx.x;
  const int lane = t & 63, wid = t >> 6;
  const int wm = wid >> 1, wn = wid & 1;
  const int l32 = lane & 31, half = lane >> 5;
  float* outp = part + (size_t)kc * NN * DOUT;
#pragma unroll
  for (int fm = 0; fm < 2; ++fm)
#pragma unroll
    for (int fn = 0; fn < 2; ++fn) {
      int gc = n0 + wn * 64 + fn * 32 + l32;
#pragma unroll
      for (int reg = 0; reg < 16; ++reg) {
        int gr = m0 + wm * 64 + fm * 32 + (reg & 3) + 8 * (reg >> 2) + 4 * half;
        outp[(size_t)gr * DOUT + gc] = acc[fm][fn][reg];
      }
    }
}

// ---------------------------------------------------------------------------
// K6: out[i][j] = relu( d[i] * (sum of SPLITK partials) + b[j] ),  fp32 out.
// ---------------------------------------------------------------------------
__global__ __launch_bounds__(256) void k_out(
    const float* __restrict__ part, const float* __restrict__ d,
    const float* __restrict__ bias, float* __restrict__ outp) {
  int idx = blockIdx.x * 256 + threadIdx.x;   // float4 index
  int i = idx >> 7;                           // 128 f4 per row
  int j4 = idx & 127;
  float4 p = *(const float4*)(part + (size_t)idx * 4);
#pragma unroll
  for (int kc = 1; kc < SPLITK; ++kc) {
    float4 q = *(const float4*)(part + (size_t)kc * NN * DOUT + (size_t)idx * 4);
    p.x += q.x; p.y += q.y; p.z += q.z; p.w += q.w;
  }
  float4 bb = *(const float4*)(bias + j4 * 4);
  float di = d[i];
  float4 o;
  o.x = fmaxf(fmaf(di, p.x, bb.x), 0.f);
  o.y = fmaxf(fmaf(di, p.y, bb.y), 0.f);
  o.z = fmaxf(fmaf(di, p.z, bb.z), 0.f);
  o.w = fmaxf(fmaf(di, p.w, bb.w), 0.f);
  *(float4*)(outp + (size_t)idx * 4) = o;
}

// ---------------------------------------------------------------------------
// out = relu(d . ((A+I) @ ((d.x) @ W^T)) + b)   [row-scale commutes with @W^T]
// ---------------------------------------------------------------------------
extern "C" void kernel_launch(void* const* d_in, const int* in_sizes, int n_in,
                              void* d_out, int out_size, void* d_ws, size_t ws_size,
                              hipStream_t stream) {
  const float* x   = (const float*)d_in[0];   // (8192, 512)
  const float* adj = (const float*)d_in[1];   // (8192, 8192)
  const float* W   = (const float*)d_in[2];   // (512, 512) (out,in)
  const float* b   = (const float*)d_in[3];   // (512,)
  float* out = (float*)d_out;                 // (8192, 512) fp32

  char* ws = (char*)d_ws;
  bf16_t* adjb = (bf16_t*)(ws);                        // 134217728 (8192x8192 bf16, +I folded)
  float*  part = (float*)(ws + 134217728);             // SPLITK x 16 MB fp32
  bf16_t* YT   = (bf16_t*)(ws + 167772160);            // 8 MB (512x8192 bf16)
  bf16_t* dxb  = (bf16_t*)(ws + 176160768);            // 8 MB (8192x512 bf16)
  bf16_t* Wb   = (bf16_t*)(ws + 184549376);            // 0.5 MB
  float*  dvec = (float*)(ws + 185073664);             // 32 KB

  k_rowsum_convert<<<NN, 256, 0, stream>>>(adj, adjb, dvec);
  k_dx<<<(NN * DIN) / 1024, 256, 0, stream>>>(x, dvec, dxb);
  k_convert_w<<<(DOUT * DIN) / 1024, 256, 0, stream>>>(W, Wb);
  k_gemmY<<<dim3(DOUT / 128, NN / 128), 256, 0, stream>>>(Wb, dxb, YT);
  k_gemm1<<<dim3(NN / 128, DOUT / 128, SPLITK), 256, 0, stream>>>(adjb, YT, part);
  k_out<<<(NN * DOUT) / 1024, 256, 0, stream>>>(part, dvec, b, out);
}

// Round 9
// 512.425 us; speedup vs baseline: 1.0143x; 1.0007x over previous
//
#include <hip/hip_runtime.h>
#include <stdint.h>

typedef __bf16 bf16_t;
typedef __bf16 bf16x8 __attribute__((ext_vector_type(8)));
typedef __bf16 bf16x4v __attribute__((ext_vector_type(4)));
typedef float f32x16 __attribute__((ext_vector_type(16)));

#define AS_GLOBAL __attribute__((address_space(1)))
#define AS_LDS    __attribute__((address_space(3)))

static constexpr int NN   = 8192;   // nodes
static constexpr int DIN  = 512;
static constexpr int DOUT = 512;
static constexpr int SPLITK = 2;    // 512 gemm1 blocks, 2 resident/CU (64KB LDS)

// 16B async global->LDS copy (global_load_lds_dwordx4).
__device__ __forceinline__ void async_cp16(const bf16_t* g, bf16_t* l) {
  __builtin_amdgcn_global_load_lds((AS_GLOBAL unsigned int*)g,
                                   (AS_LDS unsigned int*)l, 16, 0, 0);
}

// ---------------------------------------------------------------------------
// K1: d[i] = rsqrt(sum_k adj[i,k] + 1), adjb = bf16(adj + I).
// ---------------------------------------------------------------------------
__global__ __launch_bounds__(256) void k_rowsum_convert(
    const float* __restrict__ adj, bf16_t* __restrict__ adjb,
    float* __restrict__ d) {
  const int row = blockIdx.x;
  const int t = threadIdx.x;
  const float4* rf4 = (const float4*)(adj + (size_t)row * NN);
  bf16_t* outp = adjb + (size_t)row * NN;
  const int diagF4 = row >> 2;
  float sum = 0.f;
#pragma unroll
  for (int c = 0; c < 8; ++c) {
    int f4i = c * 256 + t;               // 2048 float4 per row
    float4 a = rf4[f4i];
    sum += a.x + a.y + a.z + a.w;
    bf16x4v o;
    o[0] = (bf16_t)a.x; o[1] = (bf16_t)a.y; o[2] = (bf16_t)a.z; o[3] = (bf16_t)a.w;
    if (f4i == diagF4) {                 // fold identity into the bf16 matrix
      int s = row & 3;
      float vv = s == 0 ? a.x : s == 1 ? a.y : s == 2 ? a.z : a.w;
      o[s] = (bf16_t)(vv + 1.0f);
    }
    *(bf16x4v*)(outp + f4i * 4) = o;
  }
#pragma unroll
  for (int off = 32; off > 0; off >>= 1) sum += __shfl_down(sum, off);
  __shared__ float red[4];
  if ((t & 63) == 0) red[t >> 6] = sum;
  __syncthreads();
  if (t == 0) {
    float s = red[0] + red[1] + red[2] + red[3] + 1.0f;  // +1 for identity
    d[row] = rsqrtf(s);
  }
}

// ---------------------------------------------------------------------------
// K2: dxb[i][k] = bf16(d[i] * x[i][k])   (8192 x 512, unit stride)
// ---------------------------------------------------------------------------
__global__ __launch_bounds__(256) void k_dx(
    const float* __restrict__ x, const float* __restrict__ d,
    bf16_t* __restrict__ dxb) {
  int idx = blockIdx.x * 256 + threadIdx.x;   // float4 index
  int i = idx >> 7;                           // 128 f4 per row
  float4 v = *(const float4*)(x + (size_t)idx * 4);
  float s = d[i];
  bf16x4v o;
  o[0] = (bf16_t)(v.x * s); o[1] = (bf16_t)(v.y * s);
  o[2] = (bf16_t)(v.z * s); o[3] = (bf16_t)(v.w * s);
  *(bf16x4v*)(dxb + (size_t)idx * 4) = o;
}

// ---------------------------------------------------------------------------
// K3: Wb = bf16(W)
// ---------------------------------------------------------------------------
__global__ __launch_bounds__(256) void k_convert_w(
    const float* __restrict__ W, bf16_t* __restrict__ Wb) {
  int idx = blockIdx.x * 256 + threadIdx.x;
  float4 v = *(const float4*)(W + (size_t)idx * 4);
  bf16x4v o;
  o[0] = (bf16_t)v.x; o[1] = (bf16_t)v.y; o[2] = (bf16_t)v.z; o[3] = (bf16_t)v.w;
  *(bf16x4v*)(Wb + (size_t)idx * 4) = o;
}

// ---------------------------------------------------------------------------
// GEMM core, NT, bf16, 128x128 tile, 2-phase double-buffered:
//   prologue stage tile0 -> loop { stage t+1 into buf^1; vmcnt(8); s_barrier;
//   ds_read+MFMA on buf; lgkmcnt(0); s_barrier; flip }.
// 256 thr = 4 waves 2x2, wave 64x64 via 2x2 frags of v_mfma_f32_32x32x16_bf16.
// C/D: col=lane&31, row=(reg&3)+8*(reg>>2)+4*(lane>>5) [m74/m101].
// XOR-swizzled LDS: staging lane permutes its global source chunk, frag reads
// XOR back -> conflict-floor b128 reads.
// ---------------------------------------------------------------------------
__device__ __forceinline__ void gemm_tile_128x128_db(
    const bf16_t* __restrict__ A, const bf16_t* __restrict__ B,
    int lda, int ldb, int m0, int n0, int kStart, int kEnd,
    bf16_t* As, bf16_t* Bs, f32x16 acc[2][2]) {
  const int t = threadIdx.x;
  const int lane = t & 63;
  const int wid = t >> 6;
  const int wm = wid >> 1, wn = wid & 1;
  const int l32 = lane & 31, half = lane >> 5;

  const int swz = (t & 7) ^ ((t >> 3) & 7);
  const bf16_t* gA = A + (size_t)(m0 + (t >> 3)) * lda + swz * 8 + kStart;
  const bf16_t* gB = B + (size_t)(n0 + (t >> 3)) * ldb + swz * 8 + kStart;
  const int xorc = lane & 7;
  const int nIter = (kEnd - kStart) >> 6;

  // prologue: stage tile 0 into buffer 0 (8 loads in flight)
#pragma unroll
  for (int i = 0; i < 4; ++i) {
    async_cp16(gA + (size_t)(i * 32) * lda, As + t * 8 + i * 2048);
    async_cp16(gB + (size_t)(i * 32) * ldb, Bs + t * 8 + i * 2048);
  }
  gA += 64; gB += 64;

  int cur = 0;
  for (int it = 0; it < nIter; ++it) {
    if (it + 1 < nIter) {
      const int nb = (cur ^ 1) * 8192;   // next buffer, elements
#pragma unroll
      for (int i = 0; i < 4; ++i) {
        async_cp16(gA + (size_t)(i * 32) * lda, As + nb + t * 8 + i * 2048);
        async_cp16(gB + (size_t)(i * 32) * ldb, Bs + nb + t * 8 + i * 2048);
      }
      gA += 64; gB += 64;
      // oldest 8 (current tile) done; newest 8 (next tile) remain in flight
      asm volatile("s_waitcnt vmcnt(8)" ::: "memory");
    } else {
      asm volatile("s_waitcnt vmcnt(0)" ::: "memory");
    }
    __builtin_amdgcn_s_barrier();        // all waves' current-tile loads landed

    const bf16_t* Ab = As + cur * 8192;
    const bf16_t* Bb = Bs + cur * 8192;
#pragma unroll
    for (int ks = 0; ks < 4; ++ks) {     // 4 K-steps of 16
      const int pchunk = ((ks * 2 + half) ^ xorc) * 8;
      bf16x8 av[2], bv[2];
#pragma unroll
      for (int f = 0; f < 2; ++f) {
        av[f] = *(const bf16x8*)(Ab + (wm * 64 + f * 32 + l32) * 64 + pchunk);
        bv[f] = *(const bf16x8*)(Bb + (wn * 64 + f * 32 + l32) * 64 + pchunk);
      }
#pragma unroll
      for (int fm = 0; fm < 2; ++fm)
#pragma unroll
        for (int fn = 0; fn < 2; ++fn)
          acc[fm][fn] = __builtin_amdgcn_mfma_f32_32x32x16_bf16(
              av[fm], bv[fn], acc[fm][fn], 0, 0, 0);
    }
    // all this wave's ds_reads drained before other waves may overwrite buf
    asm volatile("s_waitcnt lgkmcnt(0)" ::: "memory");
    __builtin_amdgcn_s_barrier();
    cur ^= 1;
  }
}

// ---------------------------------------------------------------------------
// K4: YT[j][i] = bf16( sum_k Wb[j,k] * dxb[i,k] )   (512 x 8192, K=512)
// Y = (d.x) @ W^T stored transposed = k-contiguous B operand of K5.
// grid (4, 64): x = j fastest -> 4 consecutive blocks share the dxb i-panel.
// ---------------------------------------------------------------------------
__global__ __launch_bounds__(256) void k_gemmY(
    const bf16_t* __restrict__ Wb, const bf16_t* __restrict__ dxb,
    bf16_t* __restrict__ YT) {
  __shared__ __align__(16) bf16_t As[2 * 128 * 64];
  __shared__ __align__(16) bf16_t Bs[2 * 128 * 64];
  f32x16 acc[2][2];
#pragma unroll
  for (int a = 0; a < 2; ++a)
#pragma unroll
    for (int b = 0; b < 2; ++b)
#pragma unroll
      for (int r = 0; r < 16; ++r) acc[a][b][r] = 0.f;

  const int m0 = blockIdx.x * 128, n0 = blockIdx.y * 128;  // m over j, n over i
  gemm_tile_128x128_db(Wb, dxb, DIN, DIN, m0, n0, 0, DIN, As, Bs, acc);

  const int t = threadIdx.x;
  const int lane = t & 63, wid = t >> 6;
  const int wm = wid >> 1, wn = wid & 1;
  const int l32 = lane & 31, half = lane >> 5;
#pragma unroll
  for (int fm = 0; fm < 2; ++fm)
#pragma unroll
    for (int fn = 0; fn < 2; ++fn) {
      int gc = n0 + wn * 64 + fn * 32 + l32;
#pragma unroll
      for (int reg = 0; reg < 16; ++reg) {
        int gr = m0 + wm * 64 + fm * 32 + (reg & 3) + 8 * (reg >> 2) + 4 * half;
        YT[(size_t)gr * NN + gc] = (bf16_t)acc[fm][fn][reg];
      }
    }
}

// ---------------------------------------------------------------------------
// K5: gemm1 partials: part[kc][i][j] = sum_{k in chunk} adjb[i,k] * YT[j,k].
// FLAT 1D grid of 512 with XCD-chunked bijective mapping (T1, 512%8==0):
//   xcd = lin&7, within = lin>>3, c = xcd*64 + within;
//   n = c&3 (FASTEST), m = (c>>2)&63, kc = c>>8.
// Rationale (R4 theory): old grid (m fastest) dispatched the 4 n-blocks that
// share a 1MB A-panel to different XCDs at different times -> A re-fetched
// 4x from HBM (~1GB total FETCH, gemm1 HBM-bound ~200us). Now those 4 blocks
// are CONSECUTIVE ON THE SAME XCD: A-panel L2-hit after first touch, A read
// from HBM exactly once (134MB). B (YT, 8MB) is L2/L3-resident regardless.
// ---------------------------------------------------------------------------
__global__ __launch_bounds__(256) void k_gemm1(
    const bf16_t* __restrict__ adjb, const bf16_t* __restrict__ YT,
    float* __restrict__ part) {
  __shared__ __align__(16) bf16_t As[2 * 128 * 64];
  __shared__ __align__(16) bf16_t Bs[2 * 128 * 64];
  f32x16 acc[2][2];
#pragma unroll
  for (int a = 0; a < 2; ++a)
#pragma unroll
    for (int b = 0; b < 2; ++b)
#pragma unroll
      for (int r = 0; r < 16; ++r) acc[a][b][r] = 0.f;

  const int lin = blockIdx.x;               // [0, 512)
  const int c = (lin & 7) * 64 + (lin >> 3);  // XCD-chunked, bijective
  const int n0 = (c & 3) * 128;               // n fastest within chunk
  const int m0 = ((c >> 2) & 63) * 128;
  const int kc = c >> 8;
  const int kChunk = NN / SPLITK;           // 4096
  gemm_tile_128x128_db(adjb, YT, NN, NN, m0, n0, kc * kChunk, (kc + 1) * kChunk,
                       As, Bs, acc);

  const int t = threadIdx.x;
  const int lane = t & 63, wid = t >> 6;
  const int wm = wid >> 1, wn = wid & 1;
  const int l32 = lane & 31, half = lane >> 5;
  float* outp = part + (size_t)kc * NN * DOUT;
#pragma unroll
  for (int fm = 0; fm < 2; ++fm)
#pragma unroll
    for (int fn = 0; fn < 2; ++fn) {
      int gc = n0 + wn * 64 + fn * 32 + l32;
#pragma unroll
      for (int reg = 0; reg < 16; ++reg) {
        int gr = m0 + wm * 64 + fm * 32 + (reg & 3) + 8 * (reg >> 2) + 4 * half;
        outp[(size_t)gr * DOUT + gc] = acc[fm][fn][reg];
      }
    }
}

// ---------------------------------------------------------------------------
// K6: out[i][j] = relu( d[i] * (sum of SPLITK partials) + b[j] ),  fp32 out.
// ---------------------------------------------------------------------------
__global__ __launch_bounds__(256) void k_out(
    const float* __restrict__ part, const float* __restrict__ d,
    const float* __restrict__ bias, float* __restrict__ outp) {
  int idx = blockIdx.x * 256 + threadIdx.x;   // float4 index
  int i = idx >> 7;                           // 128 f4 per row
  int j4 = idx & 127;
  float4 p = *(const float4*)(part + (size_t)idx * 4);
#pragma unroll
  for (int kc = 1; kc < SPLITK; ++kc) {
    float4 q = *(const float4*)(part + (size_t)kc * NN * DOUT + (size_t)idx * 4);
    p.x += q.x; p.y += q.y; p.z += q.z; p.w += q.w;
  }
  float4 bb = *(const float4*)(bias + j4 * 4);
  float di = d[i];
  float4 o;
  o.x = fmaxf(fmaf(di, p.x, bb.x), 0.f);
  o.y = fmaxf(fmaf(di, p.y, bb.y), 0.f);
  o.z = fmaxf(fmaf(di, p.z, bb.z), 0.f);
  o.w = fmaxf(fmaf(di, p.w, bb.w), 0.f);
  *(float4*)(outp + (size_t)idx * 4) = o;
}

// ---------------------------------------------------------------------------
// out = relu(d . ((A+I) @ ((d.x) @ W^T)) + b)   [row-scale commutes with @W^T]
// ---------------------------------------------------------------------------
extern "C" void kernel_launch(void* const* d_in, const int* in_sizes, int n_in,
                              void* d_out, int out_size, void* d_ws, size_t ws_size,
                              hipStream_t stream) {
  const float* x   = (const float*)d_in[0];   // (8192, 512)
  const float* adj = (const float*)d_in[1];   // (8192, 8192)
  const float* W   = (const float*)d_in[2];   // (512, 512) (out,in)
  const float* b   = (const float*)d_in[3];   // (512,)
  float* out = (float*)d_out;                 // (8192, 512) fp32

  char* ws = (char*)d_ws;
  bf16_t* adjb = (bf16_t*)(ws);                        // 134217728 (8192x8192 bf16, +I folded)
  float*  part = (float*)(ws + 134217728);             // SPLITK x 16 MB fp32
  bf16_t* YT   = (bf16_t*)(ws + 167772160);            // 8 MB (512x8192 bf16)
  bf16_t* dxb  = (bf16_t*)(ws + 176160768);            // 8 MB (8192x512 bf16)
  bf16_t* Wb   = (bf16_t*)(ws + 184549376);            // 0.5 MB
  float*  dvec = (float*)(ws + 185073664);             // 32 KB

  k_rowsum_convert<<<NN, 256, 0, stream>>>(adj, adjb, dvec);
  k_dx<<<(NN * DIN) / 1024, 256, 0, stream>>>(x, dvec, dxb);
  k_convert_w<<<(DOUT * DIN) / 1024, 256, 0, stream>>>(W, Wb);
  k_gemmY<<<dim3(DOUT / 128, NN / 128), 256, 0, stream>>>(Wb, dxb, YT);
  k_gemm1<<<(NN / 128) * (DOUT / 128) * SPLITK, 256, 0, stream>>>(adjb, YT, part);
  k_out<<<(NN * DOUT) / 1024, 256, 0, stream>>>(part, dvec, b, out);
}

// Round 13
// 507.940 us; speedup vs baseline: 1.0232x; 1.0088x over previous
//
#include <hip/hip_runtime.h>
#include <stdint.h>

typedef __bf16 bf16_t;
typedef __bf16 bf16x8 __attribute__((ext_vector_type(8)));
typedef __bf16 bf16x4v __attribute__((ext_vector_type(4)));
typedef float f32x16 __attribute__((ext_vector_type(16)));

#define AS_GLOBAL __attribute__((address_space(1)))
#define AS_LDS    __attribute__((address_space(3)))

static constexpr int NN   = 8192;   // nodes
static constexpr int DIN  = 512;
static constexpr int DOUT = 512;
static constexpr int SPLITK = 4;    // 256x256 tile: 32m x 2n x 4kc = 256 blocks = 1/CU

// 16B async global->LDS copy (global_load_lds_dwordx4).
__device__ __forceinline__ void async_cp16(const bf16_t* g, bf16_t* l) {
  __builtin_amdgcn_global_load_lds((AS_GLOBAL unsigned int*)g,
                                   (AS_LDS unsigned int*)l, 16, 0, 0);
}

// ---------------------------------------------------------------------------
// K1: d[i]=rsqrt(rowsum+1); adjb=bf16(adj+I); dxb[i,:]=bf16(d[i]*x[i,:]);
//     rows<512 also convert W. (k_dx + k_convert_w folded in: -2 launches.)
// ---------------------------------------------------------------------------
__global__ __launch_bounds__(256) void k_rowsum_convert(
    const float* __restrict__ adj, const float* __restrict__ x,
    const float* __restrict__ W, bf16_t* __restrict__ adjb,
    bf16_t* __restrict__ dxb, bf16_t* __restrict__ Wb,
    float* __restrict__ d) {
  const int row = blockIdx.x;
  const int t = threadIdx.x;
  const float4* rf4 = (const float4*)(adj + (size_t)row * NN);
  bf16_t* outp = adjb + (size_t)row * NN;
  const int diagF4 = row >> 2;
  float sum = 0.f;
#pragma unroll
  for (int c = 0; c < 8; ++c) {
    int f4i = c * 256 + t;               // 2048 float4 per row
    float4 a = rf4[f4i];
    sum += a.x + a.y + a.z + a.w;
    bf16x4v o;
    o[0] = (bf16_t)a.x; o[1] = (bf16_t)a.y; o[2] = (bf16_t)a.z; o[3] = (bf16_t)a.w;
    if (f4i == diagF4) {                 // fold identity into the bf16 matrix
      int s = row & 3;
      float vv = s == 0 ? a.x : s == 1 ? a.y : s == 2 ? a.z : a.w;
      o[s] = (bf16_t)(vv + 1.0f);
    }
    *(bf16x4v*)(outp + f4i * 4) = o;
  }
#pragma unroll
  for (int off = 32; off > 0; off >>= 1) sum += __shfl_down(sum, off);
  __shared__ float red[4];
  if ((t & 63) == 0) red[t >> 6] = sum;
  __syncthreads();
  const float s = rsqrtf(red[0] + red[1] + red[2] + red[3] + 1.0f);  // +1 identity
  if (t == 0) d[row] = s;
  if (t < 128) {                         // dxb row: 128 float4 = 512 elems
    float4 v = *(const float4*)(x + (size_t)row * DIN + t * 4);
    bf16x4v o;
    o[0] = (bf16_t)(v.x * s); o[1] = (bf16_t)(v.y * s);
    o[2] = (bf16_t)(v.z * s); o[3] = (bf16_t)(v.w * s);
    *(bf16x4v*)(dxb + (size_t)row * DIN + t * 4) = o;
  } else if (t < 256 && row < DOUT) {    // Wb row (rows 0..511)
    int tt = t - 128;
    float4 v = *(const float4*)(W + (size_t)row * DIN + tt * 4);
    bf16x4v o;
    o[0] = (bf16_t)v.x; o[1] = (bf16_t)v.y; o[2] = (bf16_t)v.z; o[3] = (bf16_t)v.w;
    *(bf16x4v*)(Wb + (size_t)row * DIN + tt * 4) = o;
  }
}

// ---------------------------------------------------------------------------
// 128x128 GEMM core (verified R4 structure) -- still used by k_gemmY.
// 2-phase dbuf: stage t+1; vmcnt(8); barrier; ds_read+MFMA; lgkmcnt(0); barrier.
// ---------------------------------------------------------------------------
__device__ __forceinline__ void gemm_tile_128x128_db(
    const bf16_t* __restrict__ A, const bf16_t* __restrict__ B,
    int lda, int ldb, int m0, int n0, int kStart, int kEnd,
    bf16_t* As, bf16_t* Bs, f32x16 acc[2][2]) {
  const int t = threadIdx.x;
  const int lane = t & 63;
  const int wid = t >> 6;
  const int wm = wid >> 1, wn = wid & 1;
  const int l32 = lane & 31, half = lane >> 5;

  const int swz = (t & 7) ^ ((t >> 3) & 7);
  const bf16_t* gA = A + (size_t)(m0 + (t >> 3)) * lda + swz * 8 + kStart;
  const bf16_t* gB = B + (size_t)(n0 + (t >> 3)) * ldb + swz * 8 + kStart;
  const int xorc = lane & 7;
  const int nIter = (kEnd - kStart) >> 6;

#pragma unroll
  for (int i = 0; i < 4; ++i) {
    async_cp16(gA + (size_t)(i * 32) * lda, As + t * 8 + i * 2048);
    async_cp16(gB + (size_t)(i * 32) * ldb, Bs + t * 8 + i * 2048);
  }
  gA += 64; gB += 64;

  int cur = 0;
  for (int it = 0; it < nIter; ++it) {
    if (it + 1 < nIter) {
      const int nb = (cur ^ 1) * 8192;
#pragma unroll
      for (int i = 0; i < 4; ++i) {
        async_cp16(gA + (size_t)(i * 32) * lda, As + nb + t * 8 + i * 2048);
        async_cp16(gB + (size_t)(i * 32) * ldb, Bs + nb + t * 8 + i * 2048);
      }
      gA += 64; gB += 64;
      asm volatile("s_waitcnt vmcnt(8)" ::: "memory");
    } else {
      asm volatile("s_waitcnt vmcnt(0)" ::: "memory");
    }
    __builtin_amdgcn_s_barrier();

    const bf16_t* Ab = As + cur * 8192;
    const bf16_t* Bb = Bs + cur * 8192;
#pragma unroll
    for (int ks = 0; ks < 4; ++ks) {
      const int pchunk = ((ks * 2 + half) ^ xorc) * 8;
      bf16x8 av[2], bv[2];
#pragma unroll
      for (int f = 0; f < 2; ++f) {
        av[f] = *(const bf16x8*)(Ab + (wm * 64 + f * 32 + l32) * 64 + pchunk);
        bv[f] = *(const bf16x8*)(Bb + (wn * 64 + f * 32 + l32) * 64 + pchunk);
      }
#pragma unroll
      for (int fm = 0; fm < 2; ++fm)
#pragma unroll
        for (int fn = 0; fn < 2; ++fn)
          acc[fm][fn] = __builtin_amdgcn_mfma_f32_32x32x16_bf16(
              av[fm], bv[fn], acc[fm][fn], 0, 0, 0);
    }
    asm volatile("s_waitcnt lgkmcnt(0)" ::: "memory");
    __builtin_amdgcn_s_barrier();
    cur ^= 1;
  }
}

// ---------------------------------------------------------------------------
// K4: YT[j][i] = bf16( sum_k Wb[j,k] * dxb[i,k] )   (512 x 8192, K=512)
// ---------------------------------------------------------------------------
__global__ __launch_bounds__(256) void k_gemmY(
    const bf16_t* __restrict__ Wb, const bf16_t* __restrict__ dxb,
    bf16_t* __restrict__ YT) {
  __shared__ __align__(16) bf16_t As[2 * 128 * 64];
  __shared__ __align__(16) bf16_t Bs[2 * 128 * 64];
  f32x16 acc[2][2];
#pragma unroll
  for (int a = 0; a < 2; ++a)
#pragma unroll
    for (int b = 0; b < 2; ++b)
#pragma unroll
      for (int r = 0; r < 16; ++r) acc[a][b][r] = 0.f;

  const int m0 = blockIdx.x * 128, n0 = blockIdx.y * 128;  // m over j, n over i
  gemm_tile_128x128_db(Wb, dxb, DIN, DIN, m0, n0, 0, DIN, As, Bs, acc);

  const int t = threadIdx.x;
  const int lane = t & 63, wid = t >> 6;
  const int wm = wid >> 1, wn = wid & 1;
  const int l32 = lane & 31, half = lane >> 5;
#pragma unroll
  for (int fm = 0; fm < 2; ++fm)
#pragma unroll
    for (int fn = 0; fn < 2; ++fn) {
      int gc = n0 + wn * 64 + fn * 32 + l32;
#pragma unroll
      for (int reg = 0; reg < 16; ++reg) {
        int gr = m0 + wm * 64 + fm * 32 + (reg & 3) + 8 * (reg >> 2) + 4 * half;
        YT[(size_t)gr * NN + gc] = (bf16_t)acc[fm][fn][reg];
      }
    }
}

// ---------------------------------------------------------------------------
// K5: gemm1, 256x256 TILE (R9 change). Staged bytes = M*N*K*2*(1/BM+1/BN):
//   128^2 -> 1.07 GB; 256^2 -> 537 MB. R4/R9 showed time invariant to
//   placement/pipeline -> staging throughput is the invariant suspect; halve it.
// 512 thr = 8 waves (2m x 4n), wave tile 128x64 = 4x2 frags of 32x32x16.
// SPLITK=4 -> 256 blocks = 1/CU (128 KB LDS dbuf). 8 loads/iter as before
// (4 passes x 64 rows for A and B) -> identical vmcnt(8) discipline.
// Same XOR swizzle: physical chunk p of row r holds global chunk p^(r&7);
// frag rows are l32 mod 8 = lane&7 -> same xorc read-back.
// XCD-chunk: c=(lin&7)*32+(lin>>3); n=c&1, m=(c>>1)&31, kc=c>>6 -> per XCD:
// 2 B-panels (2 MB, L2-resident), A streamed with 2 concurrent sharers.
// ---------------------------------------------------------------------------
__global__ __launch_bounds__(512, 2) void k_gemm1(
    const bf16_t* __restrict__ adjb, const bf16_t* __restrict__ YT,
    float* __restrict__ part) {
  __shared__ __align__(16) bf16_t As[2 * 256 * 64];   // 64 KB
  __shared__ __align__(16) bf16_t Bs[2 * 256 * 64];   // 64 KB
  f32x16 acc[4][2];
#pragma unroll
  for (int a = 0; a < 4; ++a)
#pragma unroll
    for (int b = 0; b < 2; ++b)
#pragma unroll
      for (int r = 0; r < 16; ++r) acc[a][b][r] = 0.f;

  const int lin = blockIdx.x;                 // [0,256)
  const int c = (lin & 7) * 32 + (lin >> 3);  // XCD-chunked, bijective (256%8==0)
  const int n0 = (c & 1) * 256;
  const int m0 = ((c >> 1) & 31) * 256;
  const int kc = c >> 6;
  const int kStart = kc * (NN / SPLITK);      // 2048-wide K chunk
  const int nIter = (NN / SPLITK) >> 6;       // 32

  const int t = threadIdx.x;
  const int lane = t & 63;
  const int wid = t >> 6;
  const int wm = wid >> 2, wn = wid & 3;      // 2m x 4n waves
  const int l32 = lane & 31, half = lane >> 5;
  const int xorc = lane & 7;

  const int swz = (t & 7) ^ ((t >> 3) & 7);
  const bf16_t* gA = adjb + (size_t)(m0 + (t >> 3)) * NN + swz * 8 + kStart;
  const bf16_t* gB = YT   + (size_t)(n0 + (t >> 3)) * NN + swz * 8 + kStart;

  // prologue: tile 0 (8 loads: 4 A passes of 64 rows + 4 B passes)
#pragma unroll
  for (int i = 0; i < 4; ++i) {
    async_cp16(gA + (size_t)(i * 64) * NN, As + t * 8 + i * 4096);
    async_cp16(gB + (size_t)(i * 64) * NN, Bs + t * 8 + i * 4096);
  }
  gA += 64; gB += 64;

  int cur = 0;
  for (int it = 0; it < nIter; ++it) {
    if (it + 1 < nIter) {
      const int nb = (cur ^ 1) * 16384;
#pragma unroll
      for (int i = 0; i < 4; ++i) {
        async_cp16(gA + (size_t)(i * 64) * NN, As + nb + t * 8 + i * 4096);
        async_cp16(gB + (size_t)(i * 64) * NN, Bs + nb + t * 8 + i * 4096);
      }
      gA += 64; gB += 64;
      asm volatile("s_waitcnt vmcnt(8)" ::: "memory");
    } else {
      asm volatile("s_waitcnt vmcnt(0)" ::: "memory");
    }
    __builtin_amdgcn_s_barrier();

    const bf16_t* Ab = As + cur * 16384;
    const bf16_t* Bb = Bs + cur * 16384;
#pragma unroll
    for (int ks = 0; ks < 4; ++ks) {
      const int pchunk = ((ks * 2 + half) ^ xorc) * 8;
      bf16x8 av[4], bv[2];
#pragma unroll
      for (int f = 0; f < 4; ++f)
        av[f] = *(const bf16x8*)(Ab + (wm * 128 + f * 32 + l32) * 64 + pchunk);
#pragma unroll
      for (int f = 0; f < 2; ++f)
        bv[f] = *(const bf16x8*)(Bb + (wn * 64 + f * 32 + l32) * 64 + pchunk);
#pragma unroll
      for (int fm = 0; fm < 4; ++fm)
#pragma unroll
        for (int fn = 0; fn < 2; ++fn)
          acc[fm][fn] = __builtin_amdgcn_mfma_f32_32x32x16_bf16(
              av[fm], bv[fn], acc[fm][fn], 0, 0, 0);
    }
    asm volatile("s_waitcnt lgkmcnt(0)" ::: "memory");
    __builtin_amdgcn_s_barrier();
    cur ^= 1;
  }

  float* outp = part + (size_t)kc * NN * DOUT;
#pragma unroll
  for (int fm = 0; fm < 4; ++fm)
#pragma unroll
    for (int fn = 0; fn < 2; ++fn) {
      int gc = n0 + wn * 64 + fn * 32 + l32;
#pragma unroll
      for (int reg = 0; reg < 16; ++reg) {
        int gr = m0 + wm * 128 + fm * 32 + (reg & 3) + 8 * (reg >> 2) + 4 * half;
        outp[(size_t)gr * DOUT + gc] = acc[fm][fn][reg];
      }
    }
}

// ---------------------------------------------------------------------------
// K6: out[i][j] = relu( d[i] * (sum of SPLITK partials) + b[j] ),  fp32 out.
// ---------------------------------------------------------------------------
__global__ __launch_bounds__(256) void k_out(
    const float* __restrict__ part, const float* __restrict__ d,
    const float* __restrict__ bias, float* __restrict__ outp) {
  int idx = blockIdx.x * 256 + threadIdx.x;   // float4 index
  int i = idx >> 7;                           // 128 f4 per row
  int j4 = idx & 127;
  float4 p = *(const float4*)(part + (size_t)idx * 4);
#pragma unroll
  for (int kc = 1; kc < SPLITK; ++kc) {
    float4 q = *(const float4*)(part + (size_t)kc * NN * DOUT + (size_t)idx * 4);
    p.x += q.x; p.y += q.y; p.z += q.z; p.w += q.w;
  }
  float4 bb = *(const float4*)(bias + j4 * 4);
  float di = d[i];
  float4 o;
  o.x = fmaxf(fmaf(di, p.x, bb.x), 0.f);
  o.y = fmaxf(fmaf(di, p.y, bb.y), 0.f);
  o.z = fmaxf(fmaf(di, p.z, bb.z), 0.f);
  o.w = fmaxf(fmaf(di, p.w, bb.w), 0.f);
  *(float4*)(outp + (size_t)idx * 4) = o;
}

// ---------------------------------------------------------------------------
// out = relu(d . ((A+I) @ ((d.x) @ W^T)) + b)   [row-scale commutes with @W^T]
// ---------------------------------------------------------------------------
extern "C" void kernel_launch(void* const* d_in, const int* in_sizes, int n_in,
                              void* d_out, int out_size, void* d_ws, size_t ws_size,
                              hipStream_t stream) {
  const float* x   = (const float*)d_in[0];   // (8192, 512)
  const float* adj = (const float*)d_in[1];   // (8192, 8192)
  const float* W   = (const float*)d_in[2];   // (512, 512) (out,in)
  const float* b   = (const float*)d_in[3];   // (512,)
  float* out = (float*)d_out;                 // (8192, 512) fp32

  char* ws = (char*)d_ws;
  bf16_t* adjb = (bf16_t*)(ws);                        // 134 MB (8192x8192 bf16, +I folded)
  float*  part = (float*)(ws + 134217728);             // SPLITK x 16 MB fp32 = 64 MB
  bf16_t* YT   = (bf16_t*)(ws + 201326592);            // 8 MB (512x8192 bf16)
  bf16_t* dxb  = (bf16_t*)(ws + 209715200);            // 8 MB (8192x512 bf16)
  bf16_t* Wb   = (bf16_t*)(ws + 218103808);            // 0.5 MB
  float*  dvec = (float*)(ws + 218628096);             // 32 KB

  k_rowsum_convert<<<NN, 256, 0, stream>>>(adj, x, W, adjb, dxb, Wb, dvec);
  k_gemmY<<<dim3(DOUT / 128, NN / 128), 256, 0, stream>>>(Wb, dxb, YT);
  k_gemm1<<<(NN / 256) * (DOUT / 256) * SPLITK, 512, 0, stream>>>(adjb, YT, part);
  k_out<<<(NN * DOUT) / 1024, 256, 0, stream>>>(part, dvec, b, out);
}